// Round 1
// baseline (648.606 us; speedup 1.0000x reference)
//
#include <hip/hip_runtime.h>

#define RESO 256
#define NCH 27
#define PTS_PER_BLK 32

__global__ __launch_bounds__(256) void sg_sample_kernel(
    const float* __restrict__ points,
    const float* __restrict__ dens,
    const float* __restrict__ sh,
    const int*   __restrict__ links,
    float* __restrict__ out_d,
    float* __restrict__ out_sh,
    int n)
{
    __shared__ float s_w[PTS_PER_BLK][8];     // trilinear weight (0 if invalid corner)
    __shared__ int   s_addr[PTS_PER_BLK][8];  // lnk*27 (0 if invalid)
    __shared__ float s_wd[PTS_PER_BLK][8];    // w * density (0 if invalid)

    const int tid = threadIdx.x;
    const int pl  = tid >> 3;   // local point 0..31
    const int c   = tid & 7;    // corner 0..7 (dx*4+dy*2+dz)
    const int pg  = blockIdx.x * PTS_PER_BLK + pl;

    if (pg < n) {
        const float px = points[3*pg+0];
        const float py = points[3*pg+1];
        const float pz = points[3*pg+2];

        // pos = clip(p*128 + 127.5, 0, 255); l = clip(floor(pos), 0, 254); t = pos - l
        const float posx = fminf(fmaxf(px*128.0f + 127.5f, 0.0f), 255.0f);
        const float posy = fminf(fmaxf(py*128.0f + 127.5f, 0.0f), 255.0f);
        const float posz = fminf(fmaxf(pz*128.0f + 127.5f, 0.0f), 255.0f);
        const float lxf = fminf(floorf(posx), 254.0f);
        const float lyf = fminf(floorf(posy), 254.0f);
        const float lzf = fminf(floorf(posz), 254.0f);
        const float tx = posx - lxf;
        const float ty = posy - lyf;
        const float tz = posz - lzf;
        const int base = ((int)lxf << 16) | ((int)lyf << 8) | (int)lzf;
        const int off  = ((c & 4) << 14) + ((c & 2) << 7) + (c & 1);

        const int lnk = links[base + off];

        const float wx = (c & 4) ? tx : 1.0f - tx;
        const float wy = (c & 2) ? ty : 1.0f - ty;
        const float wz = (c & 1) ? tz : 1.0f - tz;
        const float w  = (wx * wy) * wz;

        const bool valid = (lnk >= 0);
        s_w[pl][c]    = valid ? w : 0.0f;
        s_addr[pl][c] = valid ? lnk * NCH : 0;
        s_wd[pl][c]   = valid ? w * dens[lnk] : 0.0f;
    } else {
        s_w[pl][c]    = 0.0f;
        s_addr[pl][c] = 0;
        s_wd[pl][c]   = 0.0f;
    }
    __syncthreads();

    // Phase 2: (point, channel) sweep. 32 pts * 28 ch = 896 items, 256 threads.
    #pragma unroll
    for (int k = 0; k < (PTS_PER_BLK * 28 + 255) / 256; ++k) {
        const int item = tid + k * 256;
        if (item >= PTS_PER_BLK * 28) break;
        const int p = item / 28;
        const int j = item - p * 28;
        const int pg2 = blockIdx.x * PTS_PER_BLK + p;
        if (pg2 >= n) continue;
        if (j == 0) {
            float a = 0.0f;
            #pragma unroll
            for (int cc = 0; cc < 8; ++cc) a += s_wd[p][cc];
            out_d[pg2] = a;
        } else {
            const int q = j - 1;
            float acc = 0.0f;
            #pragma unroll
            for (int cc = 0; cc < 8; ++cc) {
                const float w = s_w[p][cc];
                if (w != 0.0f) acc += w * sh[s_addr[p][cc] + q];
            }
            out_sh[pg2 * NCH + q] = acc;
        }
    }
}

extern "C" void kernel_launch(void* const* d_in, const int* in_sizes, int n_in,
                              void* d_out, int out_size, void* d_ws, size_t ws_size,
                              hipStream_t stream) {
    const float* points = (const float*)d_in[0];
    const float* dens   = (const float*)d_in[1];
    const float* sh     = (const float*)d_in[2];
    const int*   links  = (const int*)d_in[3];
    const int n = in_sizes[0] / 3;

    float* out_d  = (float*)d_out;
    float* out_sh = out_d + n;

    const int grid = (n + PTS_PER_BLK - 1) / PTS_PER_BLK;
    hipLaunchKernelGGL(sg_sample_kernel, dim3(grid), dim3(256), 0, stream,
                       points, dens, sh, links, out_d, out_sh, n);
}

// Round 6
// 466.666 us; speedup vs baseline: 1.3899x; 1.3899x over previous
//
#include <hip/hip_runtime.h>

#define RESO 256
#define NCH 27
#define PTS_PER_BLK 32
#define ITEMS (PTS_PER_BLK * 28)   // 896 work items: 32 points x (1 density + 27 SH)

__global__ __launch_bounds__(256) void sg_sample_kernel(
    const float* __restrict__ points,
    const float* __restrict__ dens,
    const float* __restrict__ sh,
    const int*   __restrict__ links,
    float* __restrict__ out_d,
    float* __restrict__ out_sh,
    int n)
{
    __shared__ float s_w[PTS_PER_BLK][8];     // trilinear weight (0 if invalid corner)
    __shared__ int   s_addr[PTS_PER_BLK][8];  // lnk*27 (0 if invalid)
    __shared__ float s_wd[PTS_PER_BLK][8];    // w * density (0 if invalid)

    const int tid = threadIdx.x;
    const int pl  = tid >> 3;   // local point 0..31
    const int c   = tid & 7;    // corner 0..7 (dx*4+dy*2+dz)
    const int pg  = blockIdx.x * PTS_PER_BLK + pl;

    if (pg < n) {
        const float px = points[3*pg+0];
        const float py = points[3*pg+1];
        const float pz = points[3*pg+2];

        // pos = clip(p*128 + 127.5, 0, 255); l = clip(floor(pos), 0, 254); t = pos - l
        const float posx = fminf(fmaxf(px*128.0f + 127.5f, 0.0f), 255.0f);
        const float posy = fminf(fmaxf(py*128.0f + 127.5f, 0.0f), 255.0f);
        const float posz = fminf(fmaxf(pz*128.0f + 127.5f, 0.0f), 255.0f);
        const float lxf = fminf(floorf(posx), 254.0f);
        const float lyf = fminf(floorf(posy), 254.0f);
        const float lzf = fminf(floorf(posz), 254.0f);
        const float tx = posx - lxf;
        const float ty = posy - lyf;
        const float tz = posz - lzf;
        const int base = ((int)lxf << 16) | ((int)lyf << 8) | (int)lzf;
        const int off  = ((c & 4) << 14) + ((c & 2) << 7) + (c & 1);

        const int lnk = links[base + off];

        const float wx = (c & 4) ? tx : 1.0f - tx;
        const float wy = (c & 2) ? ty : 1.0f - ty;
        const float wz = (c & 1) ? tz : 1.0f - tz;
        const float w  = (wx * wy) * wz;

        const bool valid = (lnk >= 0);
        s_w[pl][c]    = valid ? w : 0.0f;
        s_addr[pl][c] = valid ? lnk * NCH : 0;
        s_wd[pl][c]   = valid ? w * dens[lnk] : 0.0f;
    } else {
        s_w[pl][c]    = 0.0f;
        s_addr[pl][c] = 0;
        s_wd[pl][c]   = 0.0f;
    }
    __syncthreads();

    const int base_pt = blockIdx.x * PTS_PER_BLK;

    // Phase 2: 896 items over 256 threads, processed in 2 batches of 2 items
    // each. Within a batch: issue ALL corner loads (up to 16 in flight) into
    // distinct temporaries, then reduce + store. Breaks the serial
    // load->fma->load chain that left us latency-bound at VGPR=12.
    #pragma unroll
    for (int kk = 0; kk < 2; ++kk) {
        float vals[2][8];
        float wreg[2][8];
        int   pp[2], jj[2];
        bool  live[2], isden[2];

        #pragma unroll
        for (int u = 0; u < 2; ++u) {
            const int item = tid + (kk * 2 + u) * 256;
            live[u] = (item < ITEMS);
            const int p = live[u] ? (item / 28) : 0;
            const int j = live[u] ? (item - p * 28) : 1;
            pp[u] = p; jj[u] = j;
            isden[u] = (j == 0);
            if (live[u] && !isden[u]) {
                const int q = j - 1;
                #pragma unroll
                for (int cc = 0; cc < 8; ++cc) {
                    const float w = s_w[p][cc];
                    wreg[u][cc] = w;
                    vals[u][cc] = (w != 0.0f) ? sh[s_addr[p][cc] + q] : 0.0f;
                }
            }
        }

        #pragma unroll
        for (int u = 0; u < 2; ++u) {
            if (!live[u]) continue;
            const int pg2 = base_pt + pp[u];
            if (pg2 >= n) continue;
            if (isden[u]) {
                float a = 0.0f;
                #pragma unroll
                for (int cc = 0; cc < 8; ++cc) a += s_wd[pp[u]][cc];
                out_d[pg2] = a;
            } else {
                float acc0 = 0.0f, acc1 = 0.0f;
                #pragma unroll
                for (int cc = 0; cc < 8; cc += 2) {
                    acc0 += wreg[u][cc]     * vals[u][cc];
                    acc1 += wreg[u][cc + 1] * vals[u][cc + 1];
                }
                out_sh[pg2 * NCH + (jj[u] - 1)] = acc0 + acc1;
            }
        }
    }
}

extern "C" void kernel_launch(void* const* d_in, const int* in_sizes, int n_in,
                              void* d_out, int out_size, void* d_ws, size_t ws_size,
                              hipStream_t stream) {
    const float* points = (const float*)d_in[0];
    const float* dens   = (const float*)d_in[1];
    const float* sh     = (const float*)d_in[2];
    const int*   links  = (const int*)d_in[3];
    const int n = in_sizes[0] / 3;

    float* out_d  = (float*)d_out;
    float* out_sh = out_d + n;

    const int grid = (n + PTS_PER_BLK - 1) / PTS_PER_BLK;
    hipLaunchKernelGGL(sg_sample_kernel, dim3(grid), dim3(256), 0, stream,
                       points, dens, sh, links, out_d, out_sh, n);
}

// Round 7
// 451.946 us; speedup vs baseline: 1.4351x; 1.0326x over previous
//
#include <hip/hip_runtime.h>

#define RESO 256
#define NCH 27
#define PTS_PER_BLK 32
#define ITEMS (PTS_PER_BLK * 28)   // 896 work items: 32 points x (1 density + 27 SH)

__global__ __launch_bounds__(256) void sg_sample_kernel(
    const float* __restrict__ points,
    const float* __restrict__ dens,
    const float* __restrict__ sh,
    const int*   __restrict__ links,
    float* __restrict__ out_d,
    float* __restrict__ out_sh,
    int n)
{
    __shared__ float s_w[PTS_PER_BLK][8];     // trilinear weight (0 if invalid corner)
    __shared__ int   s_addr[PTS_PER_BLK][8];  // lnk*27 (0 if invalid -> row 0, harmless)
    __shared__ float s_wd[PTS_PER_BLK][8];    // w * density (0 if invalid)

    const int tid = threadIdx.x;
    const int pl  = tid >> 3;   // local point 0..31
    const int c   = tid & 7;    // corner 0..7 (dx*4+dy*2+dz)
    const int pg  = blockIdx.x * PTS_PER_BLK + pl;

    if (pg < n) {
        const float px = points[3*pg+0];
        const float py = points[3*pg+1];
        const float pz = points[3*pg+2];

        // pos = clip(p*128 + 127.5, 0, 255); l = clip(floor(pos), 0, 254); t = pos - l
        const float posx = fminf(fmaxf(px*128.0f + 127.5f, 0.0f), 255.0f);
        const float posy = fminf(fmaxf(py*128.0f + 127.5f, 0.0f), 255.0f);
        const float posz = fminf(fmaxf(pz*128.0f + 127.5f, 0.0f), 255.0f);
        const float lxf = fminf(floorf(posx), 254.0f);
        const float lyf = fminf(floorf(posy), 254.0f);
        const float lzf = fminf(floorf(posz), 254.0f);
        const float tx = posx - lxf;
        const float ty = posy - lyf;
        const float tz = posz - lzf;
        const int base = ((int)lxf << 16) | ((int)lyf << 8) | (int)lzf;
        const int off  = ((c & 4) << 14) + ((c & 2) << 7) + (c & 1);

        const int lnk = links[base + off];

        const float wx = (c & 4) ? tx : 1.0f - tx;
        const float wy = (c & 2) ? ty : 1.0f - ty;
        const float wz = (c & 1) ? tz : 1.0f - tz;
        const float w  = (wx * wy) * wz;

        // branchless validity: invalid corner -> weight 0, row 0 (cached, harmless)
        const int   safe = (lnk >= 0) ? lnk : 0;
        const float wv   = (lnk >= 0) ? w : 0.0f;
        s_w[pl][c]    = wv;
        s_addr[pl][c] = safe * NCH;
        s_wd[pl][c]   = wv * dens[safe];
    } else {
        s_w[pl][c]    = 0.0f;
        s_addr[pl][c] = 0;
        s_wd[pl][c]   = 0.0f;
    }
    __syncthreads();

    const int base_pt = blockIdx.x * PTS_PER_BLK;

    // Phase 2: 896 items over 256 threads, 4 items/thread. ALL 32 corner loads
    // issued in ONE branchless burst (invalid corners read row 0 and get
    // multiplied by w=0), then reduce + store. Maximizes in-flight misses.
    float vals[4][8];
    int   pp[4], jj[4];

    #pragma unroll
    for (int u = 0; u < 4; ++u) {
        const int item = tid + u * 256;
        const int it   = (item < ITEMS) ? item : 0;   // dead items alias item 0 (cached)
        const int p = it / 28;
        const int j = it - p * 28;
        pp[u] = p; jj[u] = j;
        const int q = (j == 0) ? 0 : j - 1;           // density items load q=0 (L1 hit)
        #pragma unroll
        for (int cc = 0; cc < 8; ++cc) {
            vals[u][cc] = sh[s_addr[p][cc] + q];
        }
    }

    #pragma unroll
    for (int u = 0; u < 4; ++u) {
        const int item = tid + u * 256;
        if (item >= ITEMS) continue;
        const int p = pp[u], j = jj[u];
        const int pg2 = base_pt + p;
        if (pg2 >= n) continue;
        if (j == 0) {
            float a = 0.0f;
            #pragma unroll
            for (int cc = 0; cc < 8; ++cc) a += s_wd[p][cc];
            out_d[pg2] = a;
        } else {
            float acc0 = 0.0f, acc1 = 0.0f;
            #pragma unroll
            for (int cc = 0; cc < 8; cc += 2) {
                acc0 += s_w[p][cc]     * vals[u][cc];
                acc1 += s_w[p][cc + 1] * vals[u][cc + 1];
            }
            out_sh[pg2 * NCH + (j - 1)] = acc0 + acc1;
        }
    }
}

extern "C" void kernel_launch(void* const* d_in, const int* in_sizes, int n_in,
                              void* d_out, int out_size, void* d_ws, size_t ws_size,
                              hipStream_t stream) {
    const float* points = (const float*)d_in[0];
    const float* dens   = (const float*)d_in[1];
    const float* sh     = (const float*)d_in[2];
    const int*   links  = (const int*)d_in[3];
    const int n = in_sizes[0] / 3;

    float* out_d  = (float*)d_out;
    float* out_sh = out_d + n;

    const int grid = (n + PTS_PER_BLK - 1) / PTS_PER_BLK;
    hipLaunchKernelGGL(sg_sample_kernel, dim3(grid), dim3(256), 0, stream,
                       points, dens, sh, links, out_d, out_sh, n);
}